// Round 4
// baseline (139.769 us; speedup 1.0000x reference)
//
#include <hip/hip_runtime.h>
#include <hip/hip_fp16.h>

// NeuronToSpatialGrid: out[b,e,p] = (sum_n w F[b,n,e]) / (sum_n w + 1e-8),
//   w = exp(-50 dx^2) * exp(-50 dy^2)  (separable).
// R4: grid 1024 (4 blocks/CU, 16 waves/CU), block 128m(2gx x 64gy) x 32e,
// A = EY from global (frag-ordered), ex folded into B (bp = ex*F), frag-ordered
// conflict-free LDS, BK=64 double-buffered, 1 barrier / 8 MFMAs.

typedef __attribute__((ext_vector_type(8))) _Float16 half8;
typedef __attribute__((ext_vector_type(2))) _Float16 half2v;
typedef __attribute__((ext_vector_type(4))) float floatx4;

#define NB 4
#define NN 4096
#define NE 256
#define NP 4096

#if defined(__has_builtin)
#if __has_builtin(__builtin_amdgcn_fdot2)
#define HAVE_FDOT2 1
#endif
#endif

__device__ inline float dot8(half8 a, half8 b, float s) {
#ifdef HAVE_FDOT2
    half2v* pa = (half2v*)&a;
    half2v* pb = (half2v*)&b;
#pragma unroll
    for (int j = 0; j < 4; j++) s = __builtin_amdgcn_fdot2(pa[j], pb[j], s, false);
#else
#pragma unroll
    for (int j = 0; j < 8; j++) s += (float)a[j] * (float)b[j];
#endif
    return s;
}

#define MFMA16(a, bb, c) __builtin_amdgcn_mfma_f32_16x16x32_f16(a, bb, c, 0, 0, 0)

// ---------- aux kernel: [0,1024) transpose F->FT,  [1024,1536) EY table ----------
// FT[b][e][n] f16.  EYf[b][ko 512][g4 4][fr 16][j 8] = exp(-50*((g4*16+fr)/63 - y_{ko*8+j})^2)
__global__ __launch_bounds__(256) void aux_kernel(const float* __restrict__ in,
                                                  const float* __restrict__ pos,
                                                  __half* __restrict__ ft,
                                                  __half* __restrict__ EYf) {
    __shared__ float tile[128][33];
    const int bid = blockIdx.x;
    const int tid = threadIdx.x;
    if (bid < 1024) {
        const int nb = bid & 31, eb = (bid >> 5) & 7, b = bid >> 8;
        const int n0 = nb * 128, e0 = eb * 32;
        const int rn = tid >> 3, re = (tid & 7) * 4;
#pragma unroll
        for (int p = 0; p < 4; p++) {
            const int n = p * 32 + rn;
            float4 v = *(const float4*)&in[(size_t)(b * NN + n0 + n) * NE + e0 + re];
            tile[n][re] = v.x; tile[n][re + 1] = v.y; tile[n][re + 2] = v.z; tile[n][re + 3] = v.w;
        }
        __syncthreads();
        const int we = tid >> 6, wn = (tid & 63) * 2;
#pragma unroll
        for (int p = 0; p < 8; p++) {
            const int e = p * 4 + we;
            __half2 h = __floats2half2_rn(tile[wn][e], tile[wn + 1][e]);
            *(__half2*)&ft[(size_t)(b * NE + e0 + e) * NN + n0 + wn] = h;
        }
    } else {
        const int idx = (bid - 1024) * 256 + tid;     // one 8-elem chunk per thread
        const int fr = idx & 15;
        const int g4 = (idx >> 4) & 3;
        const int ko = (idx >> 6) & 511;
        const int b  = idx >> 15;
        const float gy = (float)(g4 * 16 + fr) * (1.0f / 63.0f);
        const float* pb = pos + (size_t)b * NN * 2;
        half8 h;
#pragma unroll
        for (int j = 0; j < 8; j++) {
            const float y = pb[(ko * 8 + j) * 2 + 1];
            const float d = gy - y;
            h[j] = (_Float16)__expf(d * d * -50.0f);
        }
        *(half8*)(EYf + (size_t)idx * 8) = h;
    }
}

// ---------- main fused GEMM ----------
// grid 1024: bid&7 = et (e-slice of 32, XCD-pinned); (bid>>3): b = /32, mp = %32.
// Block tile: 128m (gx in {2mp,2mp+1} x 64 gy) x 32e x K4096, BK=64.
// 4 waves = (gyh in 2) x (eg in 2); wave = 64m x 16e, 8 MFMAs/substep.
__global__ __launch_bounds__(256, 4) void nw_gemm(const __half* __restrict__ FT,   // [B][E][N]
                                                  const __half* __restrict__ EYf,  // frag order
                                                  const float* __restrict__ pos,   // [B][N][2]
                                                  float* __restrict__ out) {       // [B][E][P]
    __shared__ __half Bt_s[2][2048];      // 2 x 4 KB frag-ordered feature tile (32e x 64k)
    __shared__ __half ex_s[2 * NN];       // 16 KB: exp(-50(gx-x_k)^2), gx = 2mp (+0,+1)
    __shared__ float S_s[128];

    const int bid = blockIdx.x;
    const int et  = bid & 7;
    const int rem = bid >> 3;
    const int b   = rem >> 5;
    const int mp  = rem & 31;
    const int tid = threadIdx.x;

    // --- ex_s: 2 x 4096 exps once per block ---
    {
        const float gx0v = (float)(2 * mp) * (1.0f / 63.0f);
        const float2* pg = (const float2*)(pos + (size_t)b * NN * 2);
        for (int i = tid; i < NN; i += 256) {
            float2 q = pg[i];
            float d0 = gx0v - q.x;
            float d1 = d0 + (1.0f / 63.0f);
            ex_s[i]      = __float2half_rn(__expf(d0 * d0 * -50.0f));
            ex_s[NN + i] = __float2half_rn(__expf(d1 * d1 * -50.0f));
        }
    }

    // --- B staging: thread tid -> chunk c=tid: egc=tid>>7, ko=(tid>>4)&7, fr=tid&15 ---
    const int srow = et * 32 + ((tid >> 7) << 4) + (tid & 15);
    const __half* bsrc_t = FT + ((size_t)b * NE + srow) * NN + (((tid >> 4) & 7) << 3);

    // --- wave mapping ---
    const int wave = tid >> 6, lane = tid & 63;
    const int gyh = wave >> 1;            // gy half: rows gyh*32 .. +31
    const int eg  = wave & 1;             // e-group of 16
    const int fr = lane & 15, quad = lane >> 4;
    const int quad8 = quad * 8;
    const int g40 = gyh * 2, g41 = gyh * 2 + 1;

    const __half* eyp = EYf + ((size_t)b << 18) + fr * 8;

    floatx4 acc00 = {}, acc01 = {}, acc10 = {}, acc11 = {};   // acc[x][h]
    float s0 = 0.f, s1 = 0.f;                                 // row sums for x=eg, h=0/1

    // --- prologue: ey(ks=0), stage tile0, prefetch tile1 ---
    uint4 bv = *(const uint4*)(bsrc_t);
    half8 eyA0 = *(const half8*)(eyp + ((0 + quad) * 4 + g40) * 128);
    half8 eyA1 = *(const half8*)(eyp + ((0 + quad) * 4 + g41) * 128);
    half8 eyB0 = *(const half8*)(eyp + ((4 + quad) * 4 + g40) * 128);
    half8 eyB1 = *(const half8*)(eyp + ((4 + quad) * 4 + g41) * 128);
    *(uint4*)(&Bt_s[0][tid * 8]) = bv;
    bv = *(const uint4*)(bsrc_t + 64);

    auto substep = [&](int ksv, int cb, int nbuf) {
        __syncthreads();                                   // cb ready; nbuf reads done
        *(uint4*)(&Bt_s[nbuf][tid * 8]) = bv;              // stage tile(ksv+64)
        bv = *(const uint4*)(bsrc_t + ((ksv + 128) & (NN - 1)));
        half8 exA0 = *(const half8*)(&ex_s[ksv + quad8]);
        half8 exA1 = *(const half8*)(&ex_s[NN + ksv + quad8]);
        half8 exB0 = *(const half8*)(&ex_s[ksv + 32 + quad8]);
        half8 exB1 = *(const half8*)(&ex_s[NN + ksv + 32 + quad8]);
        half8 bfA = *(const half8*)(&Bt_s[cb][(eg * 128 + lane) * 8]);
        half8 bfB = *(const half8*)(&Bt_s[cb][(eg * 128 + lane) * 8 + 512]);
        half8 bpA0 = exA0 * bfA, bpA1 = exA1 * bfA;
        half8 bpB0 = exB0 * bfB, bpB1 = exB1 * bfB;
        acc00 = MFMA16(eyA0, bpA0, acc00);
        acc01 = MFMA16(eyA1, bpA0, acc01);
        acc10 = MFMA16(eyA0, bpA1, acc10);
        acc11 = MFMA16(eyA1, bpA1, acc11);
        acc00 = MFMA16(eyB0, bpB0, acc00);
        acc01 = MFMA16(eyB1, bpB0, acc01);
        acc10 = MFMA16(eyB0, bpB1, acc10);
        acc11 = MFMA16(eyB1, bpB1, acc11);
        // row sums for x = eg (balanced across the 2 e-waves)
        half8 exsA = eg ? exA1 : exA0;
        half8 exsB = eg ? exB1 : exB0;
        s0 = dot8(exsA, eyA0, s0); s0 = dot8(exsB, eyB0, s0);
        s1 = dot8(exsA, eyA1, s1); s1 = dot8(exsB, eyB1, s1);
        // ey prefetch for next substep
        const int ko2 = ((ksv + 64) & (NN - 1)) >> 3;
        eyA0 = *(const half8*)(eyp + ((ko2 + quad) * 4 + g40) * 128);
        eyA1 = *(const half8*)(eyp + ((ko2 + quad) * 4 + g41) * 128);
        eyB0 = *(const half8*)(eyp + ((ko2 + 4 + quad) * 4 + g40) * 128);
        eyB1 = *(const half8*)(eyp + ((ko2 + 4 + quad) * 4 + g41) * 128);
    };

    for (int ks = 0; ks < NN; ks += 128) {
        substep(ks, 0, 1);
        substep(ks + 64, 1, 0);
    }

    // --- row-sum reduce over quads; rows x=eg, gy = gyh*32 + h*16 + fr ---
    s0 += __shfl_xor(s0, 16, 64); s0 += __shfl_xor(s0, 32, 64);
    s1 += __shfl_xor(s1, 16, 64); s1 += __shfl_xor(s1, 32, 64);
    if (quad == 0) {
        S_s[eg * 64 + gyh * 32 + fr]      = 1.0f / (s0 + 1e-8f);
        S_s[eg * 64 + gyh * 32 + 16 + fr] = 1.0f / (s1 + 1e-8f);
    }
    __syncthreads();

    // --- epilogue: normalize, float4 stores along p ---
    const int e = et * 32 + eg * 16 + fr;
    float* outr = out + ((size_t)b * NE + e) * NP;
    const int gybase = gyh * 32 + quad * 4;
#pragma unroll
    for (int x = 0; x < 2; x++) {
        const int pb = (2 * mp + x) * 64 + gybase;
        {
            floatx4 sv = *(const floatx4*)(&S_s[x * 64 + gybase]);
            floatx4 o = x ? acc10 : acc00;
            o.x *= sv.x; o.y *= sv.y; o.z *= sv.z; o.w *= sv.w;
            *(floatx4*)(&outr[pb]) = o;
        }
        {
            floatx4 sv = *(const floatx4*)(&S_s[x * 64 + gybase + 16]);
            floatx4 o = x ? acc11 : acc01;
            o.x *= sv.x; o.y *= sv.y; o.z *= sv.z; o.w *= sv.w;
            *(floatx4*)(&outr[pb + 16]) = o;
        }
    }
}

extern "C" void kernel_launch(void* const* d_in, const int* in_sizes, int n_in,
                              void* d_out, int out_size, void* d_ws, size_t ws_size,
                              hipStream_t stream) {
    const float* feat = (const float*)d_in[0];   // [4][4096][256] f32
    const float* pos  = (const float*)d_in[1];   // [4][4096][2]  f32
    float* out = (float*)d_out;                  // [4][256][4096] f32
    __half* FT  = (__half*)d_ws;                                        // 8.39 MB
    __half* EYf = (__half*)((char*)d_ws + (size_t)NB * NE * NN * 2);    // +2.10 MB

    hipLaunchKernelGGL(aux_kernel, dim3(1536), dim3(256), 0, stream, feat, pos, FT, EYf);
    hipLaunchKernelGGL(nw_gemm, dim3(1024), dim3(256), 0, stream, FT, EYf, pos, out);
}